// Round 17
// baseline (269.126 us; speedup 1.0000x reference)
//
#include <hip/hip_runtime.h>

#define C_IN   64
#define C_OUT  128
#define Himg   128
#define Wimg   128
#define HW     (Himg * Wimg)
#define HCOLS  34
#define XKSTR  5440            // 340 cells * 16 B per kidx row
#define WS7    114688          // taps 0..6: 7 * 8 kidx * 128 co * 16 B

typedef __bf16 bf16x8 __attribute__((ext_vector_type(8)));
typedef float  f32x16 __attribute__((ext_vector_type(16)));

__device__ __forceinline__ unsigned int pack2(float a, float b) {
  union { __bf16 h; unsigned short s; } ua, ub;
  ua.h = (__bf16)a; ub.h = (__bf16)b;
  return (unsigned int)ua.s | ((unsigned int)ub.s << 16);
}

__device__ __forceinline__ void gload_lds16(const void* g, void* l) {
  __builtin_amdgcn_global_load_lds((const __attribute__((address_space(1))) void*)g,
                                   (__attribute__((address_space(3))) void*)l, 16, 0, 0);
}

// fp32 W[co][c][3][3] -> bf16 wt, [tap][kidx][co128][ch8] 16B cells, taps 0..8
__global__ void wt_transform(const float* __restrict__ w, unsigned short* __restrict__ wt) {
  const int idx = blockIdx.x * 256 + threadIdx.x;
  if (idx >= 9 * C_OUT * C_IN) return;
  const int c   = idx & 63;
  const int co  = (idx >> 6) & 127;
  const int tap = idx >> 13;
  const int ky = tap / 3, kx = tap % 3;
  const float f = w[((co * C_IN + c) * 3 + ky) * 3 + kx];
  union { __bf16 h; unsigned short s; } u; u.h = (__bf16)f;
  wt[((tap * 8 + (c >> 3)) * 128 + co) * 8 + (c & 7)] = u.s;
}

__global__ __launch_bounds__(512, 2)
void conv_mfma(const float* __restrict__ xin, const unsigned short* __restrict__ wt,
               const float* __restrict__ bias, float* __restrict__ out) {
  __shared__ __align__(16) unsigned char Xs[8 * XKSTR];   // 43520
  __shared__ __align__(16) unsigned char Ws[WS7];         // 114688 (total 158208)

  const int tid = threadIdx.x;
  const int bid = blockIdx.x;          // 256 blocks, 1/CU
  const int s   = (bid & 7) * 32 + (bid >> 3);   // strip 0..255 (XCD-contiguous)

  const int lane = tid & 63;
  const int wv   = tid >> 6;   // 0..7
  const int lpx  = lane & 31;
  const int lkh  = lane >> 5;
  const int wm   = wv & 1;     // co 64-half
  const int wn   = wv >> 1;    // 0..3: rows 2wn, 2wn+1

  // staging role constants (R12/R14 verbatim)
  const int xi = tid & 31;            // px column
  const int kg = (tid >> 5) & 7;      // kidx
  const int hf = tid >> 8;            // row half: rows hf*5..hf*5+4
  const int hside = (tid >= 80) ? 1 : 0;      // halo (threads 0..159)
  const int hrr   = (tid - hside * 80) >> 3;  // halo row 0..9
  const int hkg   = tid & 7;

  // ---- Ws DMA: taps 0..6, all 128 co, once per block (114688 B) ----
  {
    const unsigned short* s0 = wt + tid * 8;
    #pragma unroll
    for (int j = 0; j < 14; ++j)
      gload_lds16(s0 + j * 4096, &Ws[tid * 16 + j * 8192]);
  }
  // ---- taps 7,8 A-fragments into registers, once per block ----
  bf16x8 a78[2][2][4];   // [tap-7][mf][ks]
  #pragma unroll
  for (int tp = 0; tp < 2; ++tp)
    #pragma unroll
    for (int mf = 0; mf < 2; ++mf)
      #pragma unroll
      for (int ks = 0; ks < 4; ++ks)
        a78[tp][mf][ks] = *(const bf16x8*)(wt + (size_t)(7 + tp) * 8192 +
                                           (ks * 2 + lkh) * 1024 + (wm * 64 + mf * 32 + lpx) * 8);

  float4 bq[2][4];
  #pragma unroll
  for (int mf = 0; mf < 2; ++mf)
    #pragma unroll
    for (int rq = 0; rq < 4; ++rq)
      bq[mf][rq] = *(const float4*)(bias + wm * 64 + mf * 32 + rq * 8 + lkh * 4);

  float xr[5][8];
  float hr[8];

  auto LOADX = [&](int img, int gy0, int gx0) {
    const float* pb = xin + ((size_t)img * C_IN + kg * 8) * HW + gx0 + xi;
    #pragma unroll
    for (int j = 0; j < 5; ++j) {
      const int gy = gy0 - 1 + hf * 5 + j;
      if (gy >= 0 && gy < Himg) {
        const float* p = pb + (size_t)gy * Wimg;
        #pragma unroll
        for (int ch = 0; ch < 8; ++ch) xr[j][ch] = p[(size_t)ch * HW];
      } else {
        #pragma unroll
        for (int ch = 0; ch < 8; ++ch) xr[j][ch] = 0.f;
      }
    }
    if (tid < 160) {
      const int gx = hside ? gx0 + 32 : gx0 - 1;
      const int gy = gy0 - 1 + hrr;
      if (gy >= 0 && gy < Himg && gx >= 0 && gx < Wimg) {
        const float* p = xin + ((size_t)img * C_IN + hkg * 8) * HW + (size_t)gy * Wimg + gx;
        #pragma unroll
        for (int ch = 0; ch < 8; ++ch) hr[ch] = p[(size_t)ch * HW];
      } else {
        #pragma unroll
        for (int ch = 0; ch < 8; ++ch) hr[ch] = 0.f;
      }
    }
  };

  auto WRITEX = [&]() {
    #pragma unroll
    for (int j = 0; j < 5; ++j) {
      uint4 cell;
      cell.x = pack2(xr[j][0], xr[j][1]); cell.y = pack2(xr[j][2], xr[j][3]);
      cell.z = pack2(xr[j][4], xr[j][5]); cell.w = pack2(xr[j][6], xr[j][7]);
      *(uint4*)(&Xs[kg * XKSTR + ((hf * 5 + j) * HCOLS + 1 + xi) * 16]) = cell;
    }
    if (tid < 160) {
      uint4 cell;
      cell.x = pack2(hr[0], hr[1]); cell.y = pack2(hr[2], hr[3]);
      cell.z = pack2(hr[4], hr[5]); cell.w = pack2(hr[6], hr[7]);
      *(uint4*)(&Xs[hkg * XKSTR + (hrr * HCOLS + (hside ? 33 : 0)) * 16]) = cell;
    }
  };

  // tile decode: 2304 tiles; 64/img (16 gy x 4 gx), gy fastest
  auto TDEC = [&](int ts, int& img, int& gy0, int& gx0) {
    img = ts >> 6;
    const int rem = ts & 63;
    gy0 = (rem & 15) * 8;
    gx0 = (rem >> 4) * 32;
  };

  // ---- prologue: stage tile 0 ----
  {
    int img, gy0, gx0;
    TDEC(s * 9, img, gy0, gx0);
    LOADX(img, gy0, gx0);
    WRITEX();
  }
  __syncthreads();   // drains Ws DMA + Xs ds_writes

  f32x16 acc[2][2];
  #pragma unroll
  for (int mf = 0; mf < 2; ++mf)
    #pragma unroll
    for (int nf = 0; nf < 2; ++nf)
      acc[mf][nf] = (f32x16)(0.f);

  #pragma unroll 1
  for (int i = 0; i < 9; ++i) {
    int cimg, cgy0, cgx0;
    TDEC(s * 9 + i, cimg, cgy0, cgx0);

    if (i < 8) {   // T14: issue next tile's loads; consumed by WRITEX after compute
      int nimg, ngy0, ngx0;
      TDEC(s * 9 + i + 1, nimg, ngy0, ngx0);
      LOADX(nimg, ngy0, ngx0);
    }

    // ---- compute: taps 0..6 A from LDS, taps 7,8 A from registers ----
    #pragma unroll
    for (int t = 0; t < 9; ++t) {
      const int dy = (t >= 6) ? 2 : (t >= 3 ? 1 : 0);
      const int dx = t - dy * 3;
      int boff[2];
      #pragma unroll
      for (int nf = 0; nf < 2; ++nf)
        boff[nf] = lkh * XKSTR + ((wn * 2 + nf + dy) * HCOLS + dx + lpx) * 16;
      #pragma unroll
      for (int ks = 0; ks < 4; ++ks) {
        bf16x8 A0, A1;
        if (t < 7) {
          const int aoff = t * 16384 + (ks * 2 + lkh) * 2048 + (wm * 64 + lpx) * 16;
          A0 = *(const bf16x8*)&Ws[aoff];
          A1 = *(const bf16x8*)&Ws[aoff + 512];
        } else {
          A0 = a78[t - 7][0][ks];
          A1 = a78[t - 7][1][ks];
        }
        bf16x8 B0 = *(const bf16x8*)&Xs[boff[0] + ks * 2 * XKSTR];
        bf16x8 B1 = *(const bf16x8*)&Xs[boff[1] + ks * 2 * XKSTR];
        acc[0][0] = __builtin_amdgcn_mfma_f32_32x32x16_bf16(A0, B0, acc[0][0], 0, 0, 0);
        acc[0][1] = __builtin_amdgcn_mfma_f32_32x32x16_bf16(A0, B1, acc[0][1], 0, 0, 0);
        acc[1][0] = __builtin_amdgcn_mfma_f32_32x32x16_bf16(A1, B0, acc[1][0], 0, 0, 0);
        acc[1][1] = __builtin_amdgcn_mfma_f32_32x32x16_bf16(A1, B1, acc[1][1], 0, 0, 0);
      }
    }

    // ---- stores: issued, NOT drained (overlap next tile) ----
    #pragma unroll
    for (int nf = 0; nf < 2; ++nf) {
      const int y = cgy0 + wn * 2 + nf;
      float* op = out + (size_t)cimg * C_OUT * HW + (size_t)y * Wimg + cgx0 + lpx;
      #pragma unroll
      for (int mf = 0; mf < 2; ++mf) {
        #pragma unroll
        for (int r = 0; r < 16; ++r) {
          const int co = wm * 64 + mf * 32 + (r & 3) + 8 * (r >> 2) + lkh * 4;
          op[(size_t)co * HW] = acc[mf][nf][r] + ((const float*)&bq[mf][r >> 2])[r & 3];
        }
      }
    }
    #pragma unroll
    for (int mf = 0; mf < 2; ++mf)
      #pragma unroll
      for (int nf = 0; nf < 2; ++nf)
        acc[mf][nf] = (f32x16)(0.f);

    if (i < 8) {
      // all waves done reading Xs (lgkm only — global stores stay in flight)
      asm volatile("s_waitcnt lgkmcnt(0)" ::: "memory");
      __builtin_amdgcn_s_barrier();
      __builtin_amdgcn_sched_barrier(0);
      WRITEX();
      asm volatile("s_waitcnt lgkmcnt(0)" ::: "memory");
      __builtin_amdgcn_s_barrier();
      __builtin_amdgcn_sched_barrier(0);
    }
  }
}

extern "C" void kernel_launch(void* const* d_in, const int* in_sizes, int n_in,
                              void* d_out, int out_size, void* d_ws, size_t ws_size,
                              hipStream_t stream) {
  const float* x    = (const float*)d_in[0];
  const float* w    = (const float*)d_in[1];
  const float* bias = (const float*)d_in[2];
  float* out = (float*)d_out;
  unsigned short* wt = (unsigned short*)d_ws;  // 9*8*128*8 bf16 = 147456 B

  wt_transform<<<(9 * C_OUT * C_IN + 255) / 256, 256, 0, stream>>>(w, wt);

  conv_mfma<<<dim3(256), 512, 0, stream>>>(x, wt, bias, out);
}

// Round 18
// 162.923 us; speedup vs baseline: 1.6519x; 1.6519x over previous
//
#include <hip/hip_runtime.h>

#define C_IN   64
#define C_OUT  128
#define Himg   128
#define Wimg   128
#define HW     (Himg * Wimg)
#define TROWS  4
#define TCOLS  32
#define HROWS  6    // TROWS+2
#define HCOLS  34   // TCOLS+2
#define XKSTR  (HROWS * HCOLS * 16)   // 3264 B per kidx row
#define WS_TAP 16384

typedef __bf16 bf16x8 __attribute__((ext_vector_type(8)));
typedef float  f32x16 __attribute__((ext_vector_type(16)));

__device__ __forceinline__ unsigned int pack2(float a, float b) {
  union { __bf16 h; unsigned short s; } ua, ub;
  ua.h = (__bf16)a; ub.h = (__bf16)b;
  return (unsigned int)ua.s | ((unsigned int)ub.s << 16);
}

__device__ __forceinline__ void gload_lds16(const void* g, void* l) {
  __builtin_amdgcn_global_load_lds((const __attribute__((address_space(1))) void*)g,
                                   (__attribute__((address_space(3))) void*)l, 16, 0, 0);
}

// fp32 W[co][c][3][3] -> bf16 wt, [tap][kidx][co128][ch8] 16B cells (R5/R8 layout, verified)
__global__ void wt_transform(const float* __restrict__ w, unsigned short* __restrict__ wt) {
  const int idx = blockIdx.x * 256 + threadIdx.x;
  if (idx >= 9 * C_OUT * C_IN) return;
  const int c   = idx & 63;
  const int co  = (idx >> 6) & 127;
  const int tap = idx >> 13;
  const int ky = tap / 3, kx = tap % 3;
  const float f = w[((co * C_IN + c) * 3 + ky) * 3 + kx];
  union { __bf16 h; unsigned short s; } u; u.h = (__bf16)f;
  wt[tap * 8192 + (c >> 3) * 1024 + co * 8 + (c & 7)] = u.s;
}

__global__ __launch_bounds__(256, 2)
void conv_mfma(const float* __restrict__ xin, const unsigned short* __restrict__ wt,
               const float* __restrict__ bias, float* __restrict__ out) {
  __shared__ __align__(16) unsigned char Xs[8 * XKSTR];    // 26112: [kidx][cell204] cells
  __shared__ __align__(16) unsigned char Ws[2][WS_TAP];    // 32768 (total 58880 -> 2 blocks/CU)

  const int tid = threadIdx.x;
  // bijective XCD swizzle: 4608 = 8 * 576; bx fastest for store-line merging
  const int wg  = (blockIdx.x & 7) * 576 + (blockIdx.x >> 3);
  const int bx  = wg & 3;
  const int by  = (wg >> 2) & 31;
  const int img = wg >> 7;
  const int gy0 = by * TROWS;
  const int gx0 = bx * TCOLS;
  const int lane = tid & 63;
  const int wv   = tid >> 6;   // 0..3
  const int lpx  = lane & 31;
  const int lkh  = lane >> 5;
  const int wm   = wv & 1;     // co 64-half
  const int wn   = wv >> 1;    // 0..1: row-pair

  // ---- issue async Ws tap-0 DMA; X staging below covers its latency ----
  #pragma unroll
  for (int j = 0; j < 4; ++j)
    gload_lds16(wt + j * 2048 + tid * 8, &Ws[0][j * 4096 + tid * 16]);

  // ---- stage X tile (fp32 -> bf16): interior + halo to registers, pack to LDS ----
  const int xi = tid & 31;        // px column
  const int kg = tid >> 5;        // kidx 0..7
  float xr[HROWS][8];
  {
    const float* pb = xin + ((size_t)img * C_IN + kg * 8) * HW + gx0 + xi;
    #pragma unroll
    for (int r = 0; r < HROWS; ++r) {
      const int gy = gy0 - 1 + r;
      if (gy >= 0 && gy < Himg) {
        const float* p = pb + (size_t)gy * Wimg;
        #pragma unroll
        for (int ch = 0; ch < 8; ++ch) xr[r][ch] = p[(size_t)ch * HW];
      } else {
        #pragma unroll
        for (int ch = 0; ch < 8; ++ch) xr[r][ch] = 0.f;
      }
    }
  }
  float hr[8];
  const int hside = (tid >= 48) ? 1 : 0;          // halo threads 0..95
  const int hrem  = tid - hside * 48;
  const int hrow  = hrem >> 3;                    // 0..5
  const int hkg   = hrem & 7;
  if (tid < 96) {
    const int gx = hside ? gx0 + TCOLS : gx0 - 1;
    const int gy = gy0 - 1 + hrow;
    if (gy >= 0 && gy < Himg && gx >= 0 && gx < Wimg) {
      const float* p = xin + ((size_t)img * C_IN + hkg * 8) * HW + (size_t)gy * Wimg + gx;
      #pragma unroll
      for (int ch = 0; ch < 8; ++ch) hr[ch] = p[(size_t)ch * HW];
    } else {
      #pragma unroll
      for (int ch = 0; ch < 8; ++ch) hr[ch] = 0.f;
    }
  }
  #pragma unroll
  for (int r = 0; r < HROWS; ++r) {
    uint4 cell;
    cell.x = pack2(xr[r][0], xr[r][1]); cell.y = pack2(xr[r][2], xr[r][3]);
    cell.z = pack2(xr[r][4], xr[r][5]); cell.w = pack2(xr[r][6], xr[r][7]);
    *(uint4*)(&Xs[kg * XKSTR + (r * HCOLS + 1 + xi) * 16]) = cell;
  }
  if (tid < 96) {
    uint4 cell;
    cell.x = pack2(hr[0], hr[1]); cell.y = pack2(hr[2], hr[3]);
    cell.z = pack2(hr[4], hr[5]); cell.w = pack2(hr[6], hr[7]);
    *(uint4*)(&Xs[hkg * XKSTR + (hrow * HCOLS + (hside ? HCOLS - 1 : 0)) * 16]) = cell;
  }

  f32x16 acc[2][2];
  #pragma unroll
  for (int mf = 0; mf < 2; ++mf)
    #pragma unroll
    for (int nf = 0; nf < 2; ++nf)
      acc[mf][nf] = (f32x16)(0.f);

  __syncthreads();   // Xs + Ws[0] ready (drains DMA)

  for (int t = 0; t < 9; ++t) {
    if (t < 8) {   // async-prefetch tap t+1 into the other buffer
      const unsigned short* sn = wt + (t + 1) * 8192 + tid * 8;
      unsigned char* db = Ws[(t + 1) & 1];
      #pragma unroll
      for (int j = 0; j < 4; ++j)
        gload_lds16(sn + j * 2048, &db[j * 4096 + tid * 16]);
    }
    const int dy = (t >= 6) ? 2 : (t >= 3 ? 1 : 0);
    const int dx = t - dy * 3;
    const unsigned char* wsb = Ws[t & 1];
    int boff[2];
    #pragma unroll
    for (int nf = 0; nf < 2; ++nf)
      boff[nf] = lkh * XKSTR + ((wn * 2 + nf + dy) * HCOLS + dx + lpx) * 16;
    const int abase = lkh * 2048 + (wm * 64 + lpx) * 16;
    #pragma unroll
    for (int ks = 0; ks < 4; ++ks) {
      bf16x8 A0 = *(const bf16x8*)&wsb[abase + ks * 4096];
      bf16x8 A1 = *(const bf16x8*)&wsb[abase + ks * 4096 + 512];
      bf16x8 B0 = *(const bf16x8*)&Xs[boff[0] + ks * 2 * XKSTR];
      bf16x8 B1 = *(const bf16x8*)&Xs[boff[1] + ks * 2 * XKSTR];
      __builtin_amdgcn_s_setprio(1);
      acc[0][0] = __builtin_amdgcn_mfma_f32_32x32x16_bf16(A0, B0, acc[0][0], 0, 0, 0);
      acc[0][1] = __builtin_amdgcn_mfma_f32_32x32x16_bf16(A0, B1, acc[0][1], 0, 0, 0);
      acc[1][0] = __builtin_amdgcn_mfma_f32_32x32x16_bf16(A1, B0, acc[1][0], 0, 0, 0);
      acc[1][1] = __builtin_amdgcn_mfma_f32_32x32x16_bf16(A1, B1, acc[1][1], 0, 0, 0);
      __builtin_amdgcn_s_setprio(0);
    }
    if (t < 8) __syncthreads();
  }

  // ---- epilogue: bias + fp32 full-line stores ----
  #pragma unroll
  for (int nf = 0; nf < 2; ++nf) {
    const int y = gy0 + wn * 2 + nf;
    float* op = out + (size_t)img * C_OUT * HW + (size_t)y * Wimg + gx0 + lpx;
    #pragma unroll
    for (int mf = 0; mf < 2; ++mf) {
      #pragma unroll
      for (int rq = 0; rq < 4; ++rq) {
        const float4 bb = *(const float4*)(bias + wm * 64 + mf * 32 + rq * 8 + lkh * 4);
        #pragma unroll
        for (int j = 0; j < 4; ++j) {
          const int r  = rq * 4 + j;
          const int co = wm * 64 + mf * 32 + j + 8 * rq + lkh * 4;
          op[(size_t)co * HW] = acc[mf][nf][r] + (&bb.x)[j];
        }
      }
    }
  }
}

extern "C" void kernel_launch(void* const* d_in, const int* in_sizes, int n_in,
                              void* d_out, int out_size, void* d_ws, size_t ws_size,
                              hipStream_t stream) {
  const float* x    = (const float*)d_in[0];
  const float* w    = (const float*)d_in[1];
  const float* bias = (const float*)d_in[2];
  float* out = (float*)d_out;
  unsigned short* wt = (unsigned short*)d_ws;  // 147456 B

  wt_transform<<<(9 * C_OUT * C_IN + 255) / 256, 256, 0, stream>>>(w, wt);

  conv_mfma<<<dim3(4608), 256, 0, stream>>>(x, wt, bias, out);
}